// Round 1
// baseline (106.745 us; speedup 1.0000x reference)
//
#include <hip/hip_runtime.h>
#include <hip/hip_bf16.h>

// out[8192,1024] = x[8192,1024] @ W[1024,1024]^T + b   (fp32 in/out, bf16 MFMA compute)

typedef float f32x4 __attribute__((ext_vector_type(4)));
typedef __bf16 bf16x8 __attribute__((ext_vector_type(8)));
typedef unsigned short u16x4 __attribute__((ext_vector_type(4)));
typedef unsigned short u16x8 __attribute__((ext_vector_type(8)));

#define M_DIM 8192
#define N_DIM 1024
#define K_DIM 1024
#define NT (K_DIM / 32)   // 32 K-steps of BK=32

__device__ __forceinline__ u16x4 cvt4(f32x4 v) {
  u16x4 o;
#pragma unroll
  for (int i = 0; i < 4; ++i) {
    __bf16 h = (__bf16)v[i];              // RNE fptrunc f32->bf16 (native on gfx950)
    o[i] = __builtin_bit_cast(unsigned short, h);
  }
  return o;
}

__global__ __launch_bounds__(256, 2)
void linear_bf16_mfma(const float* __restrict__ X, const float* __restrict__ W,
                      const float* __restrict__ Bv, float* __restrict__ C) {
  // LDS: fragment-linear bf16 tiles, double-buffered. 128x32 each = 4096 elems = 8KB.
  __shared__ unsigned short Asm[2][4096];
  __shared__ unsigned short Bsm[2][4096];

  const int bid = blockIdx.x;
  // 512 WGs; ntile = bid&7 -> each XCD (default round-robin) owns one W panel.
  const int ntile = bid & 7;
  const int mtile = bid >> 3;
  const int brow = mtile * 128;
  const int bcol = ntile * 128;

  const int t = threadIdx.x;
  const int lane = t & 63;
  const int wid = t >> 6;
  const int wr = wid >> 1;   // wave row (0..1) -> 64 rows
  const int wc = wid & 1;    // wave col (0..1) -> 64 cols

  // staging: thread t loads float4 chunk sc of row (i*32 + srow8), i=0..3
  const int srow8 = t >> 3;  // 0..31
  const int sc = t & 7;      // 0..7 (float4 chunks across BK=32)

  const float* Abase = X + (size_t)(brow + srow8) * K_DIM + sc * 4;
  const float* Wbase = W + (size_t)(bcol + srow8) * K_DIM + sc * 4;

  // LDS write offsets (elements): (row>>4)*512 + (k>>3)*128 + (row&15)*8 + (k&7), k = sc*4
  int woff[4];
#pragma unroll
  for (int i = 0; i < 4; ++i) {
    int row = i * 32 + srow8;
    woff[i] = (row >> 4) * 512 + (sc >> 1) * 128 + (row & 15) * 8 + (sc & 1) * 4;
  }

  f32x4 ra[4], rb[4];

  // prologue: stage kt = 0 into buffer 0
#pragma unroll
  for (int i = 0; i < 4; ++i) {
    ra[i] = *(const f32x4*)(Abase + (size_t)i * 32 * K_DIM);
    rb[i] = *(const f32x4*)(Wbase + (size_t)i * 32 * K_DIM);
  }
#pragma unroll
  for (int i = 0; i < 4; ++i) {
    *(u16x4*)(&Asm[0][woff[i]]) = cvt4(ra[i]);
    *(u16x4*)(&Bsm[0][woff[i]]) = cvt4(rb[i]);
  }
  __syncthreads();

  f32x4 acc[4][4] = {};

  int cur = 0;
  for (int kt = 0; kt < NT; ++kt) {
    // issue next-tile global loads early (overlap with ds_read + MFMA)
    if (kt + 1 < NT) {
      const float* Ap = Abase + (size_t)(kt + 1) * 32;
      const float* Wp = Wbase + (size_t)(kt + 1) * 32;
#pragma unroll
      for (int i = 0; i < 4; ++i) {
        ra[i] = *(const f32x4*)(Ap + (size_t)i * 32 * K_DIM);
        rb[i] = *(const f32x4*)(Wp + (size_t)i * 32 * K_DIM);
      }
    }

    // fragment reads: fully linear ds_read_b128 (conflict-free)
    bf16x8 af[4], bfr[4];
#pragma unroll
    for (int m = 0; m < 4; ++m) {
      u16x8 v = *(const u16x8*)(&Asm[cur][(wr * 4 + m) * 512 + lane * 8]);
      af[m] = __builtin_bit_cast(bf16x8, v);
    }
#pragma unroll
    for (int n = 0; n < 4; ++n) {
      u16x8 v = *(const u16x8*)(&Bsm[cur][(wc * 4 + n) * 512 + lane * 8]);
      bfr[n] = __builtin_bit_cast(bf16x8, v);
    }

#pragma unroll
    for (int m = 0; m < 4; ++m)
#pragma unroll
      for (int n = 0; n < 4; ++n)
        acc[m][n] = __builtin_amdgcn_mfma_f32_16x16x32_bf16(af[m], bfr[n], acc[m][n], 0, 0, 0);

    // convert + write next tile into the other buffer
    if (kt + 1 < NT) {
#pragma unroll
      for (int i = 0; i < 4; ++i) {
        *(u16x4*)(&Asm[cur ^ 1][woff[i]]) = cvt4(ra[i]);
        *(u16x4*)(&Bsm[cur ^ 1][woff[i]]) = cvt4(rb[i]);
      }
    }
    __syncthreads();
    cur ^= 1;
  }

  // epilogue: C/D layout col = lane&15, row = (lane>>4)*4 + j  [m89-verified]
  const int rbase = brow + wr * 64 + ((lane >> 4) << 2);
  const int cbase = bcol + wc * 64 + (lane & 15);
#pragma unroll
  for (int n = 0; n < 4; ++n) {
    const int col = cbase + n * 16;
    const float bv = Bv[col];
#pragma unroll
    for (int m = 0; m < 4; ++m) {
      const int row = rbase + m * 16;
#pragma unroll
      for (int j = 0; j < 4; ++j) {
        C[(size_t)(row + j) * N_DIM + col] = acc[m][n][j] + bv;
      }
    }
  }
}

extern "C" void kernel_launch(void* const* d_in, const int* in_sizes, int n_in,
                              void* d_out, int out_size, void* d_ws, size_t ws_size,
                              hipStream_t stream) {
  const float* x = (const float*)d_in[0];   // [8192,1024] f32
  const float* W = (const float*)d_in[1];   // [1024,1024] f32
  const float* b = (const float*)d_in[2];   // [1024] f32
  float* out = (float*)d_out;               // [8192,1024] f32

  dim3 grid(M_DIM / 128 * (N_DIM / 128));   // 64*8 = 512
  dim3 block(256);
  hipLaunchKernelGGL(linear_bf16_mfma, grid, block, 0, stream, x, W, b, out);
}

// Round 2
// 48.869 us; speedup vs baseline: 2.1843x; 2.1843x over previous
//
#include <hip/hip_runtime.h>
#include <hip/hip_bf16.h>

// out[8192,1024] = x[8192,1024] @ W[1024,1024]^T + b  (fp32 in/out, bf16 MFMA compute)
// v2: 512 threads (8 waves, 2x4 wave grid, 64x32 per wave), depth-2 register
// prefetch with named sets (no runtime-indexed reg arrays), bf16 double-buffered
// fragment-linear LDS (conflict-free b128 frag reads).

typedef float f32x4 __attribute__((ext_vector_type(4)));
typedef __bf16 bf16x8 __attribute__((ext_vector_type(8)));
typedef unsigned short u16x4 __attribute__((ext_vector_type(4)));
typedef unsigned short u16x8 __attribute__((ext_vector_type(8)));

#define MD 8192
#define ND 1024
#define KD 1024
#define BM 128
#define BN 128
#define BK 32
#define NT (KD / BK)      // 32 K-steps
#define THREADS 512

__device__ __forceinline__ u16x4 cvt4(f32x4 v) {
  u16x4 o;
#pragma unroll
  for (int i = 0; i < 4; ++i) o[i] = __builtin_bit_cast(unsigned short, (__bf16)v[i]);
  return o;
}

__global__ __launch_bounds__(THREADS, 4)
void linear_mfma_v2(const float* __restrict__ X, const float* __restrict__ W,
                    const float* __restrict__ Bv, float* __restrict__ C) {
  // fragment-linear bf16 tiles, double-buffered: 128x32 = 4096 elems = 8 KB each
  __shared__ unsigned short Asm[2][BM * BK];
  __shared__ unsigned short Bsm[2][BM * BK];

  const int bid = blockIdx.x;
  const int brow = (bid >> 3) * BM;   // 64 m-tiles
  const int bcol = (bid & 7) * BN;    // 8 n-tiles -> one W panel per XCD (round-robin)

  const int t = threadIdx.x;
  const int lane = t & 63;
  const int w = t >> 6;     // 0..7
  const int wr = w >> 2;    // 0..1  (64-row half)
  const int wc = w & 3;     // 0..3  (32-col quarter)

  // staging: thread t covers rows {srow, srow+64}, k-chunk sc (f32x4)
  const int srow = t >> 3;  // 0..63
  const int sc = t & 7;     // 0..7  -> lanes 0..7 sweep 128B of one row (coalesced)

  const float* Abase = X + (size_t)(brow + srow) * KD + sc * 4;
  const float* Wbase = W + (size_t)(bcol + srow) * KD + sc * 4;

  // LDS write offsets (bf16 elems): (row>>4)*512 + (k>>3)*128 + (row&15)*8 + (k&7)
  int woff[2];
#pragma unroll
  for (int i = 0; i < 2; ++i) {
    int row = i * 64 + srow;
    woff[i] = (row >> 4) * 512 + (sc >> 1) * 128 + (row & 15) * 8 + (sc & 1) * 4;
  }

  // two named prefetch register sets (depth-2)
  f32x4 raA0, raA1, rbA0, rbA1;   // set A
  f32x4 raB0, raB1, rbB0, rbB1;   // set B

#define LOADSET(s0, s1, t0, t1, kt)                                   \
  do {                                                                \
    const float* Ap = Abase + (size_t)(kt) * BK;                      \
    const float* Wp = Wbase + (size_t)(kt) * BK;                      \
    s0 = *(const f32x4*)(Ap);                                         \
    s1 = *(const f32x4*)(Ap + (size_t)64 * KD);                       \
    t0 = *(const f32x4*)(Wp);                                         \
    t1 = *(const f32x4*)(Wp + (size_t)64 * KD);                       \
  } while (0)

#define WRITESET(buf, s0, s1, t0, t1)                                 \
  do {                                                                \
    *(u16x4*)&Asm[buf][woff[0]] = cvt4(s0);                           \
    *(u16x4*)&Asm[buf][woff[1]] = cvt4(s1);                           \
    *(u16x4*)&Bsm[buf][woff[0]] = cvt4(t0);                           \
    *(u16x4*)&Bsm[buf][woff[1]] = cvt4(t1);                           \
  } while (0)

  f32x4 acc[4][2] = {};

  // frag read offsets: lane*8 elems within a 16-row stripe -> linear, conflict-free
  const int afr = lane * 8;

#define COMPUTE(buf)                                                        \
  do {                                                                      \
    bf16x8 af[4], bfr[2];                                                   \
    _Pragma("unroll") for (int m = 0; m < 4; ++m) {                         \
      u16x8 v = *(const u16x8*)(&Asm[buf][(wr * 4 + m) * 512 + afr]);       \
      af[m] = __builtin_bit_cast(bf16x8, v);                                \
    }                                                                       \
    _Pragma("unroll") for (int n = 0; n < 2; ++n) {                         \
      u16x8 v = *(const u16x8*)(&Bsm[buf][(wc * 2 + n) * 512 + afr]);       \
      bfr[n] = __builtin_bit_cast(bf16x8, v);                               \
    }                                                                       \
    _Pragma("unroll") for (int m = 0; m < 4; ++m)                           \
      _Pragma("unroll") for (int n = 0; n < 2; ++n)                         \
        acc[m][n] = __builtin_amdgcn_mfma_f32_16x16x32_bf16(af[m], bfr[n],  \
                                                            acc[m][n], 0, 0, 0); \
  } while (0)

  // ---- prologue: L(0)->setA, L(1)->setB, write tile0, sync
  LOADSET(raA0, raA1, rbA0, rbA1, 0);
  LOADSET(raB0, raB1, rbB0, rbB1, 1);
  WRITESET(0, raA0, raA1, rbA0, rbA1);
  __syncthreads();

  // ---- main loop: 2 K-steps per iteration (buf0 on even step, buf1 on odd)
#pragma unroll 1
  for (int kt2 = 0; kt2 < NT / 2; ++kt2) {
    // EVEN step: kt = 2*kt2, reads buf0; setA free -> load L(2*kt2+2)
    if (kt2 < NT / 2 - 1) LOADSET(raA0, raA1, rbA0, rbA1, 2 * kt2 + 2);
    COMPUTE(0);
    WRITESET(1, raB0, raB1, rbB0, rbB1);   // data for kt = 2*kt2+1
    __syncthreads();

    // ODD step: kt = 2*kt2+1, reads buf1; setB free -> load L(2*kt2+3)
    if (kt2 < NT / 2 - 1) LOADSET(raB0, raB1, rbB0, rbB1, 2 * kt2 + 3);
    COMPUTE(1);
    if (kt2 < NT / 2 - 1) WRITESET(0, raA0, raA1, rbA0, rbA1);  // kt = 2*kt2+2
    __syncthreads();
  }

  // ---- epilogue: C/D layout col = lane&15, row = (lane>>4)*4 + j
  const int rbase = brow + wr * 64 + ((lane >> 4) << 2);
  const int cbase = bcol + wc * 32 + (lane & 15);
#pragma unroll
  for (int n = 0; n < 2; ++n) {
    const int col = cbase + n * 16;
    const float bv = Bv[col];
#pragma unroll
    for (int m = 0; m < 4; ++m) {
      const int row = rbase + m * 16;
#pragma unroll
      for (int j = 0; j < 4; ++j) {
        C[(size_t)(row + j) * ND + col] = acc[m][n][j] + bv;
      }
    }
  }
}

extern "C" void kernel_launch(void* const* d_in, const int* in_sizes, int n_in,
                              void* d_out, int out_size, void* d_ws, size_t ws_size,
                              hipStream_t stream) {
  const float* x = (const float*)d_in[0];   // [8192,1024] f32
  const float* W = (const float*)d_in[1];   // [1024,1024] f32
  const float* b = (const float*)d_in[2];   // [1024] f32
  float* out = (float*)d_out;               // [8192,1024] f32

  dim3 grid((MD / BM) * (ND / BN));   // 64*8 = 512
  dim3 block(THREADS);
  hipLaunchKernelGGL(linear_mfma_v2, grid, block, 0, stream, x, W, b, out);
}